// Round 12
// baseline (2081.114 us; speedup 1.0000x reference)
//
#include <hip/hip_runtime.h>
#include <cstdint>

typedef _Float16 half2_t __attribute__((ext_vector_type(2)));
typedef _Float16 half8_t __attribute__((ext_vector_type(8)));
typedef float    floatx4 __attribute__((ext_vector_type(4)));

// ---------------- workspace layout (bytes) ----------------
#define OFF_BIAS  0ull
#define SZ_BIAS   (1536ull*4)                  // b_ih + b_hh(r,z) folded, f32
#define OFF_GI    6144ull                      // gi f16 [2][32768][768] (~100.7 MB)

// ---------------- prep: bias fold only (verified) ----------------
__global__ void k_prep(const float* __restrict__ bih1, const float* __restrict__ bih2,
                       const float* __restrict__ bhh1, const float* __restrict__ bhh2,
                       float* __restrict__ biascat) {
    int q3 = blockIdx.x * 256 + threadIdx.x;
    if (q3 < 1536) {
        // fold b_ih (all gates) + b_hh (r,z only; n-gate's b_hh is inside r*(...))
        int dir = q3 >= 768;  int j = q3 - dir*768;
        const float* bi = dir ? bih2 : bih1;
        const float* bh = dir ? bhh2 : bhh1;
        biascat[q3] = bi[j] + (j < 512 ? bh[j] : 0.f);
    }
}

// ---------------- shared helper (verified in k_gemm since round 3) ----------------
__device__ __forceinline__ half8_t cvt8(float4 a, float4 b) {
    half8_t r;
    r[0] = (_Float16)a.x; r[1] = (_Float16)a.y; r[2] = (_Float16)a.z; r[3] = (_Float16)a.w;
    r[4] = (_Float16)b.x; r[5] = (_Float16)b.y; r[6] = (_Float16)b.z; r[7] = (_Float16)b.w;
    return r;
}

// ---------------- gi GEMM (verified, source-identical) ----------------
__global__ __launch_bounds__(256) void k_gemm(const float* __restrict__ x,
                                              const float* __restrict__ Wih1,
                                              const float* __restrict__ Wih2,
                                              const float* __restrict__ bias,
                                              _Float16* __restrict__ gi) {
    __shared__ __align__(16) _Float16 As[128*32];   // [m][k], LD=32
    __shared__ __align__(16) _Float16 Bs[256*32];   // [n][k], LD=32
    const int tid = threadIdx.x;
    const int m0 = blockIdx.x * 128;
    const int n0 = blockIdx.y * 256;                // 768 = 3*256: no dir straddle
    const int lane = tid & 63, wave = tid >> 6;
    const int wr = wave >> 1, wc = wave & 1;        // 2x2 waves: 64M x 128N each
    floatx4 acc[4][8];
#pragma unroll
    for (int i = 0; i < 4; ++i)
#pragma unroll
        for (int j = 0; j < 8; ++j) acc[i][j] = (floatx4)0.f;

    const float* Wsrc = (n0 < 768) ? Wih1 : Wih2;
    const int nl = (n0 < 768) ? n0 : (n0 - 768);
    const int ar = tid >> 1, ah = (tid & 1) * 16;   // A: 2 threads/row, 16 cols each
    const float* Ag = x + (size_t)(m0 + ar)*512 + ah;
    const float* Bg = Wsrc + (size_t)(nl + tid)*512; // B: 1 thread/row, 32 cols
    _Float16* Aw = As + ar*32 + ah;
    _Float16* Bw = Bs + tid*32;
    const int aoff = (wr*64  + (lane & 15))*32 + (lane >> 4)*8;
    const int boff = (wc*128 + (lane & 15))*32 + (lane >> 4)*8;

    for (int kt = 0; kt < 16; ++kt) {
        const int ko = kt*32;
        float4 a0 = *(const float4*)(Ag + ko);
        float4 a1 = *(const float4*)(Ag + ko + 4);
        float4 a2 = *(const float4*)(Ag + ko + 8);
        float4 a3 = *(const float4*)(Ag + ko + 12);
        float4 b0 = *(const float4*)(Bg + ko);
        float4 b1 = *(const float4*)(Bg + ko + 4);
        float4 b2 = *(const float4*)(Bg + ko + 8);
        float4 b3 = *(const float4*)(Bg + ko + 12);
        float4 b4 = *(const float4*)(Bg + ko + 16);
        float4 b5 = *(const float4*)(Bg + ko + 20);
        float4 b6 = *(const float4*)(Bg + ko + 24);
        float4 b7 = *(const float4*)(Bg + ko + 28);
        __syncthreads();                       // prev tile's LDS reads complete
        *(half8_t*)(Aw)      = cvt8(a0, a1);
        *(half8_t*)(Aw + 8)  = cvt8(a2, a3);
        *(half8_t*)(Bw)      = cvt8(b0, b1);
        *(half8_t*)(Bw + 8)  = cvt8(b2, b3);
        *(half8_t*)(Bw + 16) = cvt8(b4, b5);
        *(half8_t*)(Bw + 24) = cvt8(b6, b7);
        __syncthreads();
        half8_t af[4], bf[8];
#pragma unroll
        for (int f = 0; f < 4; ++f) af[f] = *(const half8_t*)(As + aoff + f*512);
#pragma unroll
        for (int f = 0; f < 8; ++f) bf[f] = *(const half8_t*)(Bs + boff + f*512);
#pragma unroll
        for (int i = 0; i < 4; ++i)
#pragma unroll
            for (int j = 0; j < 8; ++j)
                acc[i][j] = __builtin_amdgcn_mfma_f32_16x16x32_f16(af[i], bf[j], acc[i][j], 0, 0, 0);
    }
    // epilogue: +bias, f16, split into gi[dir][row][col]
#pragma unroll
    for (int i = 0; i < 4; ++i) {
#pragma unroll
        for (int j = 0; j < 8; ++j) {
            int col = n0 + wc*128 + j*16 + (lane & 15);
            float bv = bias[col];
            int dir = col >= 768;
            size_t gib = (size_t)dir * 25165824ull + (size_t)(col - dir*768);
#pragma unroll
            for (int q = 0; q < 4; ++q) {
                int row = m0 + wr*64 + i*16 + (lane >> 4)*4 + q;
                gi[gib + (size_t)row*768] = (_Float16)(acc[i][j][q] + bv);
            }
        }
    }
}

// ---------------- recurrent kernel: 1 WG per (direction, batch) sequence ----------------
// R12: T=256, thread c owns column c with FULL K=256 and all 3 gates.
// Rationale: the compiler caps multi-wave WGs (T>=512) at 65536 regs/WG (256KB)
// < W's 384KB -> forced restream at per-CU L2 port BW (measured 646us ~ the
// 2730cy/step port floor). At T=256 the allocator provably goes past 128/thread
// (m97: 164V+64A), so w[384] can be (mostly) resident. Side benefit: no K-split
// -> no part[] LDS, no partial-combine; all 4 waves do gate math.
#define FDOT2(w_, h_, acc_) __builtin_amdgcn_fdot2(__builtin_bit_cast(half2_t,(w_)), (h_), (acc_), false)
#define LBAR()  do { asm volatile("s_waitcnt lgkmcnt(0)" ::: "memory"); \
                     __builtin_amdgcn_s_barrier(); } while (0)

__global__ __launch_bounds__(256, 1) void k_rnn(const float* __restrict__ Whh1,
                                                const float* __restrict__ Whh2,
                                                const _Float16* __restrict__ gi,
                                                const float* __restrict__ mask,
                                                const float* __restrict__ bhh1,
                                                const float* __restrict__ bhh2,
                                                float* __restrict__ outp) {
    __shared__ __align__(16) _Float16 hs16[256];     // h as f16
    const int c   = threadIdx.x;                     // column this thread owns
    const int bid = blockIdx.x;                      // 0..127
    const int dir = bid >> 6, b = bid & 63;

    // W_hh rows {c, c+256, c+512}, FULL K=256, packed f16x2: w[a*128+j] =
    // pack(W[c+a*256][2j], W[c+a*256][2j+1]).  384 u32 of register file.
    const float* W = dir ? Whh2 : Whh1;              // (768, 256) row-major
    unsigned int w[384];
#pragma unroll
    for (int a = 0; a < 3; ++a) {
        const float* wrow = W + (size_t)(c + a*256)*256;
#pragma unroll
        for (int j = 0; j < 128; ++j) {
            float2 f = *(const float2*)(wrow + 2*j);
            half2_t hp = {(_Float16)f.x, (_Float16)f.y};
            w[a*128 + j] = __builtin_bit_cast(unsigned int, hp);
        }
    }
    const float bhn = (dir ? bhh2 : bhh1)[512 + c];

    hs16[c] = (_Float16)0.f;
    float h_c = 0.f;
    __syncthreads();

    const _Float16* gb = gi + (size_t)dir * 25165824ull + c;

#pragma unroll 1
    for (int s = 0; s < 512; ++s) {
        const int t = dir ? (511 - s) : s;
        // gi/mask issued first; consumed after the dot phase covers the latency
        const _Float16* gp = gb + (size_t)(t*64 + b)*768;
        float g0 = (float)gp[0];                     // i_r (+b_ih_r+b_hh_r folded)
        float g1 = (float)gp[256];                   // i_z (+b_ih_z+b_hh_z folded)
        float g2 = (float)gp[512];                   // i_n (+b_ih_n folded)
        float mv = mask[t*64 + b];

        // gh dot products: 3 gates x 256 K, f16x2 dot2, 6 chains for ILP
        float a0 = 0.f, a1 = 0.f, a2 = 0.f;
        float b0 = 0.f, b1 = 0.f, b2 = 0.f;
#pragma unroll
        for (int kk = 0; kk < 32; ++kk) {
            half8_t hv = *(const half8_t*)(hs16 + (kk << 3));  // broadcast ds_read_b128
            half2_t h0 = {hv[0], hv[1]};
            half2_t h1 = {hv[2], hv[3]};
            half2_t h2 = {hv[4], hv[5]};
            half2_t h3 = {hv[6], hv[7]};
            const int q = kk << 2;
            a0 = FDOT2(w[      q + 0], h0, a0);  b0 = FDOT2(w[      q + 1], h1, b0);
            a0 = FDOT2(w[      q + 2], h2, a0);  b0 = FDOT2(w[      q + 3], h3, b0);
            a1 = FDOT2(w[128 + q + 0], h0, a1);  b1 = FDOT2(w[128 + q + 1], h1, b1);
            a1 = FDOT2(w[128 + q + 2], h2, a1);  b1 = FDOT2(w[128 + q + 3], h3, b1);
            a2 = FDOT2(w[256 + q + 0], h0, a2);  b2 = FDOT2(w[256 + q + 1], h1, b2);
            a2 = FDOT2(w[256 + q + 2], h2, a2);  b2 = FDOT2(w[256 + q + 3], h3, b2);
        }
        float ghr = a0 + b0;
        float ghz = a1 + b1;
        float ghn = a2 + b2;
        LBAR();                                      // all hs16 reads complete
        float r = 1.f / (1.f + __expf(-(g0 + ghr)));
        float z = 1.f / (1.f + __expf(-(g1 + ghz)));
        float tt = g2 + r * (ghn + bhn);
        float ea = __expf(-2.f * fabsf(tt));         // overflow-safe tanh
        float nt = (1.f - ea) / (1.f + ea);
        nt = (tt < 0.f) ? -nt : nt;
        float ht = (1.f - z) * nt + z * h_c;
        float hm = mv * ht + (1.f - mv) * h_c;
        h_c = hm;
        hs16[c] = (_Float16)hm;                      // typed f16 store
        outp[(size_t)(t*64 + b)*512 + dir*256 + c] = mv * ht;  // ack never drained
        LBAR();                                      // hs16 visible for next step
    }
    outp[16777216u + dir*16384 + b*256 + c] = h_c;   // hidden[dir][b][c]
}

// ---------------- launch ----------------
extern "C" void kernel_launch(void* const* d_in, const int* in_sizes, int n_in,
                              void* d_out, int out_size, void* d_ws, size_t ws_size,
                              hipStream_t stream) {
    const float* x    = (const float*)d_in[0];
    const float* mask = (const float*)d_in[1];
    const float* Wih1 = (const float*)d_in[2];
    const float* Whh1 = (const float*)d_in[3];
    const float* bih1 = (const float*)d_in[4];
    const float* bhh1 = (const float*)d_in[5];
    const float* Wih2 = (const float*)d_in[6];
    const float* Whh2 = (const float*)d_in[7];
    const float* bih2 = (const float*)d_in[8];
    const float* bhh2 = (const float*)d_in[9];
    char* ws = (char*)d_ws;
    float* biascat = (float*)(ws + OFF_BIAS);
    _Float16* gi   = (_Float16*)(ws + OFF_GI);
    float* outp = (float*)d_out;

    hipLaunchKernelGGL(k_prep, dim3(6), dim3(256), 0, stream,
                       bih1, bih2, bhh1, bhh2, biascat);
    hipLaunchKernelGGL(k_gemm, dim3(256, 6), dim3(256), 0, stream, x, Wih1, Wih2, biascat, gi);
    hipLaunchKernelGGL(k_rnn, dim3(128), dim3(256), 0, stream,
                       Whh1, Whh2, gi, mask, bhh1, bhh2, outp);
}

// Round 13
// 857.886 us; speedup vs baseline: 2.4259x; 2.4259x over previous
//
#include <hip/hip_runtime.h>
#include <cstdint>

typedef _Float16 half2_t __attribute__((ext_vector_type(2)));
typedef _Float16 half8_t __attribute__((ext_vector_type(8)));
typedef float    floatx4 __attribute__((ext_vector_type(4)));

// ---------------- workspace layout (bytes) ----------------
#define OFF_BIAS  0ull
#define SZ_BIAS   (1536ull*4)                  // b_ih + b_hh(r,z) folded, f32
#define OFF_GI    6144ull                      // gi f16 [2][32768][768] (~100.7 MB)

// ---------------- prep: bias fold only (verified) ----------------
__global__ void k_prep(const float* __restrict__ bih1, const float* __restrict__ bih2,
                       const float* __restrict__ bhh1, const float* __restrict__ bhh2,
                       float* __restrict__ biascat) {
    int q3 = blockIdx.x * 256 + threadIdx.x;
    if (q3 < 1536) {
        // fold b_ih (all gates) + b_hh (r,z only; n-gate's b_hh is inside r*(...))
        int dir = q3 >= 768;  int j = q3 - dir*768;
        const float* bi = dir ? bih2 : bih1;
        const float* bh = dir ? bhh2 : bhh1;
        biascat[q3] = bi[j] + (j < 512 ? bh[j] : 0.f);
    }
}

// ---------------- shared helper (verified in k_gemm since round 3) ----------------
__device__ __forceinline__ half8_t cvt8(float4 a, float4 b) {
    half8_t r;
    r[0] = (_Float16)a.x; r[1] = (_Float16)a.y; r[2] = (_Float16)a.z; r[3] = (_Float16)a.w;
    r[4] = (_Float16)b.x; r[5] = (_Float16)b.y; r[6] = (_Float16)b.z; r[7] = (_Float16)b.w;
    return r;
}

// ---------------- gi GEMM (verified, source-identical) ----------------
__global__ __launch_bounds__(256) void k_gemm(const float* __restrict__ x,
                                              const float* __restrict__ Wih1,
                                              const float* __restrict__ Wih2,
                                              const float* __restrict__ bias,
                                              _Float16* __restrict__ gi) {
    __shared__ __align__(16) _Float16 As[128*32];   // [m][k], LD=32
    __shared__ __align__(16) _Float16 Bs[256*32];   // [n][k], LD=32
    const int tid = threadIdx.x;
    const int m0 = blockIdx.x * 128;
    const int n0 = blockIdx.y * 256;                // 768 = 3*256: no dir straddle
    const int lane = tid & 63, wave = tid >> 6;
    const int wr = wave >> 1, wc = wave & 1;        // 2x2 waves: 64M x 128N each
    floatx4 acc[4][8];
#pragma unroll
    for (int i = 0; i < 4; ++i)
#pragma unroll
        for (int j = 0; j < 8; ++j) acc[i][j] = (floatx4)0.f;

    const float* Wsrc = (n0 < 768) ? Wih1 : Wih2;
    const int nl = (n0 < 768) ? n0 : (n0 - 768);
    const int ar = tid >> 1, ah = (tid & 1) * 16;   // A: 2 threads/row, 16 cols each
    const float* Ag = x + (size_t)(m0 + ar)*512 + ah;
    const float* Bg = Wsrc + (size_t)(nl + tid)*512; // B: 1 thread/row, 32 cols
    _Float16* Aw = As + ar*32 + ah;
    _Float16* Bw = Bs + tid*32;
    const int aoff = (wr*64  + (lane & 15))*32 + (lane >> 4)*8;
    const int boff = (wc*128 + (lane & 15))*32 + (lane >> 4)*8;

    for (int kt = 0; kt < 16; ++kt) {
        const int ko = kt*32;
        float4 a0 = *(const float4*)(Ag + ko);
        float4 a1 = *(const float4*)(Ag + ko + 4);
        float4 a2 = *(const float4*)(Ag + ko + 8);
        float4 a3 = *(const float4*)(Ag + ko + 12);
        float4 b0 = *(const float4*)(Bg + ko);
        float4 b1 = *(const float4*)(Bg + ko + 4);
        float4 b2 = *(const float4*)(Bg + ko + 8);
        float4 b3 = *(const float4*)(Bg + ko + 12);
        float4 b4 = *(const float4*)(Bg + ko + 16);
        float4 b5 = *(const float4*)(Bg + ko + 20);
        float4 b6 = *(const float4*)(Bg + ko + 24);
        float4 b7 = *(const float4*)(Bg + ko + 28);
        __syncthreads();                       // prev tile's LDS reads complete
        *(half8_t*)(Aw)      = cvt8(a0, a1);
        *(half8_t*)(Aw + 8)  = cvt8(a2, a3);
        *(half8_t*)(Bw)      = cvt8(b0, b1);
        *(half8_t*)(Bw + 8)  = cvt8(b2, b3);
        *(half8_t*)(Bw + 16) = cvt8(b4, b5);
        *(half8_t*)(Bw + 24) = cvt8(b6, b7);
        __syncthreads();
        half8_t af[4], bf[8];
#pragma unroll
        for (int f = 0; f < 4; ++f) af[f] = *(const half8_t*)(As + aoff + f*512);
#pragma unroll
        for (int f = 0; f < 8; ++f) bf[f] = *(const half8_t*)(Bs + boff + f*512);
#pragma unroll
        for (int i = 0; i < 4; ++i)
#pragma unroll
            for (int j = 0; j < 8; ++j)
                acc[i][j] = __builtin_amdgcn_mfma_f32_16x16x32_f16(af[i], bf[j], acc[i][j], 0, 0, 0);
    }
    // epilogue: +bias, f16, split into gi[dir][row][col]
#pragma unroll
    for (int i = 0; i < 4; ++i) {
#pragma unroll
        for (int j = 0; j < 8; ++j) {
            int col = n0 + wc*128 + j*16 + (lane & 15);
            float bv = bias[col];
            int dir = col >= 768;
            size_t gib = (size_t)dir * 25165824ull + (size_t)(col - dir*768);
#pragma unroll
            for (int q = 0; q < 4; ++q) {
                int row = m0 + wr*64 + i*16 + (lane >> 4)*4 + q;
                gi[gib + (size_t)row*768] = (_Float16)(acc[i][j][q] + bv);
            }
        }
    }
}

// ---------------- recurrent kernel: 1 WG per (direction, batch) sequence ----------------
// R13: R7-exact verified body + amdgpu_num_vgpr(240). The backend's register
// budget defaults to 65536 regs/WG (measured: T=512->128, T=1024->64, i.e.
// 256KB/WG) while W needs 384KB/WG -> forced restream at ~127 B/cy/CU (646us).
// amdgpu_num_vgpr directly overrides getMaxNumVGPRs (unlike waves_per_eu /
// launch_bounds min-waves / LDS padding, all measured-ignored R7/R11).
// 240 regs -> 2 waves/SIMD tier; 8-wave WG still fits 1 WG/CU.
#define FDOT2(w_, h_, acc_) __builtin_amdgcn_fdot2(__builtin_bit_cast(half2_t,(w_)), (h_), (acc_), false)
#define LBAR()  do { asm volatile("s_waitcnt lgkmcnt(0)" ::: "memory"); \
                     __builtin_amdgcn_s_barrier(); } while (0)

__global__ __launch_bounds__(512) __attribute__((amdgpu_num_vgpr(240)))
void k_rnn(const float* __restrict__ Whh1,
           const float* __restrict__ Whh2,
           const _Float16* __restrict__ gi,
           const float* __restrict__ mask,
           const float* __restrict__ bhh1,
           const float* __restrict__ bhh2,
           float* __restrict__ outp) {
    __shared__ __align__(16) _Float16 hs16[256];     // h as f16
    __shared__ float part[768];                      // kh=1 partial sums
    const int tid = threadIdx.x;
    const int bid = blockIdx.x;                      // 0..127
    const int dir = bid >> 6, b = bid & 63;
    const int c  = tid & 255;                        // column this thread owns
    const int kh = tid >> 8;                         // K half

    // W_hh rows {c, c+256, c+512}, k in [kh*128, kh*128+128), packed f16x2 in-register.
    const float* W = dir ? Whh2 : Whh1;              // (768, 256) row-major
    unsigned int w[192];
#pragma unroll
    for (int a = 0; a < 3; ++a) {
        const float* wrow = W + (size_t)(c + a*256)*256 + kh*128;
#pragma unroll
        for (int qq = 0; qq < 64; ++qq) {
            float2 f = *(const float2*)(wrow + 2*qq);
            half2_t hp = {(_Float16)f.x, (_Float16)f.y};
            w[a*64 + qq] = __builtin_bit_cast(unsigned int, hp);
        }
    }
    const float bhn = (dir ? bhh2 : bhh1)[512 + c];

    if (tid < 256) hs16[tid] = (_Float16)0.f;
    float h_c = 0.f;
    __syncthreads();

    const _Float16* gb = gi + (size_t)dir * 25165824ull + c;
    const _Float16* hrd = hs16 + (kh << 7);          // this thread's K-half base

#pragma unroll 1
    for (int s = 0; s < 512; ++s) {
        const int t = dir ? (511 - s) : s;
        float g0 = 0.f, g1 = 0.f, g2 = 0.f, mv = 0.f;
        if (tid < 256) {
            // issued here, consumed after barrier 1 -> dot phase covers latency
            const _Float16* gp = gb + (size_t)(t*64 + b)*768;
            g0 = (float)gp[0];                       // i_r (+b_ih_r+b_hh_r folded)
            g1 = (float)gp[256];                     // i_z (+b_ih_z+b_hh_z folded)
            g2 = (float)gp[512];                     // i_n (+b_ih_n folded)
            mv = mask[t*64 + b];
        }
        // gh dot products: 3 gate rows x 128 K-values, f16x2 dot2
        float a0 = 0.f, a1 = 0.f, a2 = 0.f;
        float b0 = 0.f, b1 = 0.f, b2 = 0.f;          // second chains for ILP
#pragma unroll
        for (int kk = 0; kk < 16; ++kk) {
            half8_t hv = *(const half8_t*)(hrd + (kk << 3));  // broadcast ds_read_b128
            half2_t h0 = {hv[0], hv[1]};
            half2_t h1 = {hv[2], hv[3]};
            half2_t h2 = {hv[4], hv[5]};
            half2_t h3 = {hv[6], hv[7]};
            const int q = kk << 2;
            a0 = FDOT2(w[      q + 0], h0, a0);  b0 = FDOT2(w[      q + 1], h1, b0);
            a0 = FDOT2(w[      q + 2], h2, a0);  b0 = FDOT2(w[      q + 3], h3, b0);
            a1 = FDOT2(w[ 64 + q + 0], h0, a1);  b1 = FDOT2(w[ 64 + q + 1], h1, b1);
            a1 = FDOT2(w[ 64 + q + 2], h2, a1);  b1 = FDOT2(w[ 64 + q + 3], h3, b1);
            a2 = FDOT2(w[128 + q + 0], h0, a2);  b2 = FDOT2(w[128 + q + 1], h1, b2);
            a2 = FDOT2(w[128 + q + 2], h2, a2);  b2 = FDOT2(w[128 + q + 3], h3, b2);
        }
        a0 += b0; a1 += b1; a2 += b2;
        if (tid >= 256) { part[c] = a0; part[256 + c] = a1; part[512 + c] = a2; }
        LBAR();                                      // part visible; hs16 reads done
        if (tid < 256) {
            float ghr = a0 + part[c];
            float ghz = a1 + part[256 + c];
            float ghn = a2 + part[512 + c];
            float r = 1.f / (1.f + __expf(-(g0 + ghr)));
            float z = 1.f / (1.f + __expf(-(g1 + ghz)));
            float tt = g2 + r * (ghn + bhn);
            float ea = __expf(-2.f * fabsf(tt));     // overflow-safe tanh
            float nt = (1.f - ea) / (1.f + ea);
            nt = (tt < 0.f) ? -nt : nt;
            float ht = (1.f - z) * nt + z * h_c;
            float hm = mv * ht + (1.f - mv) * h_c;
            h_c = hm;
            hs16[c] = (_Float16)hm;                  // typed f16 store
            outp[(size_t)(t*64 + b)*512 + dir*256 + c] = mv * ht;  // ack never drained
        }
        LBAR();                                      // hs16 visible for next step
    }
    if (tid < 256) {
        outp[16777216u + dir*16384 + b*256 + c] = h_c;   // hidden[dir][b][c]
    }
}

// ---------------- launch ----------------
extern "C" void kernel_launch(void* const* d_in, const int* in_sizes, int n_in,
                              void* d_out, int out_size, void* d_ws, size_t ws_size,
                              hipStream_t stream) {
    const float* x    = (const float*)d_in[0];
    const float* mask = (const float*)d_in[1];
    const float* Wih1 = (const float*)d_in[2];
    const float* Whh1 = (const float*)d_in[3];
    const float* bih1 = (const float*)d_in[4];
    const float* bhh1 = (const float*)d_in[5];
    const float* Wih2 = (const float*)d_in[6];
    const float* Whh2 = (const float*)d_in[7];
    const float* bih2 = (const float*)d_in[8];
    const float* bhh2 = (const float*)d_in[9];
    char* ws = (char*)d_ws;
    float* biascat = (float*)(ws + OFF_BIAS);
    _Float16* gi   = (_Float16*)(ws + OFF_GI);
    float* outp = (float*)d_out;

    hipLaunchKernelGGL(k_prep, dim3(6), dim3(256), 0, stream,
                       bih1, bih2, bhh1, bhh2, biascat);
    hipLaunchKernelGGL(k_gemm, dim3(256, 6), dim3(256), 0, stream, x, Wih1, Wih2, biascat, gi);
    hipLaunchKernelGGL(k_rnn, dim3(128), dim3(512), 0, stream,
                       Whh1, Whh2, gi, mask, bhh1, bhh2, outp);
}